// Round 3
// baseline (6181.593 us; speedup 1.0000x reference)
//
#include <hip/hip_runtime.h>
#include <stdint.h>

// R3: 64 rows/block, pairwise N-split (2 blocks per row-group, same XCD),
// halves per-CU L2 weight stream: 2.16 -> 1.0 MB/step. K=512 exactly (x/bias
// applied as fp32 VALU epilogue). LDS A-tile 64x512 bf16 = 64 KB, XOR-swizzled
// 16B chunks (chunk' = chunk ^ (row&7)) to break stride-512 bank alignment.
// Pair exchange: 32 KB h-half via L2 + release/acquire flags (prep zeroes them
// every launch; ws is re-poisoned 0xAA so flags MUST be re-zeroed each call).

#define WMAT 1048576          // shorts per packed matrix (16 ntL * 32 kt * 4 g * 512)
#define XSTR 32768            // shorts per xchg group (64 rows * 512)
#define B_TOT 4096

typedef __attribute__((ext_vector_type(8))) short short8;
typedef __attribute__((ext_vector_type(16))) float floatx16;

__device__ __forceinline__ unsigned short f2bf(float x) {
  union { float f; unsigned int u; } v; v.f = x;
  unsigned int u = v.u;
  return (unsigned short)((u + 0x7FFFu + ((u >> 16) & 1u)) >> 16);
}
__device__ __forceinline__ float bf2f(unsigned short s) {
  union { unsigned int u; float f; } v; v.u = ((unsigned int)s) << 16;
  return v.f;
}
__device__ __forceinline__ float rcpf(float x) { return __builtin_amdgcn_rcpf(x); }
__device__ __forceinline__ float sigm(float x) { return rcpf(1.0f + __expf(-x)); }
__device__ __forceinline__ float tanh_f(float x) {
  return 1.0f - 2.0f * rcpf(1.0f + __expf(2.0f * x));
}

// ---------------- prep: pack Wh (bf16, MFMA-B layout) + zero hsum/csum/flags --
__global__ void prep_weights(
    const float* __restrict__ Wh_s, const float* __restrict__ Wh_p,
    const float* __restrict__ Wh_d, const float* __restrict__ Wh_i,
    short* __restrict__ wpack, float* __restrict__ hsum, float* __restrict__ csum,
    int* __restrict__ flags)
{
  int idx = blockIdx.x * 256 + threadIdx.x;
  if (idx < 2097152) { hsum[idx] = 0.0f; csum[idx] = 0.0f; }
  if (idx < 1024) flags[idx] = 0;
  const int per = 2048 * 512;
  if (idx >= 4 * per) return;
  int mat = idx / per;
  int rem = idx - mat * per;
  int n = rem >> 9;
  int ka = rem & 511;
  const float* Wh = (mat == 0) ? Wh_s : (mat == 1) ? Wh_p : (mat == 2) ? Wh_d : Wh_i;
  float v = Wh[n * 512 + ka];
  int g = n >> 9, ntL = (n >> 5) & 15, ni = n & 31;
  int kt = ka >> 4, kh = (ka >> 3) & 1, ks = ka & 7;
  int lanep = kh * 32 + ni;
  wpack[(size_t)mat * WMAT + ((((ntL * 32 + kt) * 4 + g) << 9) + (lanep << 3) + ks)] =
      (short)f2bf(v);
}

// ---------------- gate matmul: acc[mt][gate] over K=512, 2 M-tiles ----------
__device__ __forceinline__ void gate_mfma(
    const short* hl, const short* __restrict__ bp0,
    int arow, int ahalf, int sw, floatx16 acc[2][4])
{
  #pragma unroll
  for (int mt = 0; mt < 2; ++mt)
    #pragma unroll
    for (int g = 0; g < 4; ++g) acc[mt][g] = (floatx16)0.0f;
  const short* bp = bp0;
  #pragma unroll 4
  for (int kt = 0; kt < 32; ++kt) {
    int ci = (((kt << 1) | ahalf) ^ sw) << 3;
    short8 a0 = *(const short8*)(hl + arow * 512 + ci);
    short8 a1 = *(const short8*)(hl + 16384 + arow * 512 + ci);
    short8 b0 = *(const short8*)(bp);
    short8 b1 = *(const short8*)(bp + 512);
    short8 b2 = *(const short8*)(bp + 1024);
    short8 b3 = *(const short8*)(bp + 1536);
    bp += 2048;
    acc[0][0] = __builtin_amdgcn_mfma_f32_32x32x16_bf16(a0, b0, acc[0][0], 0, 0, 0);
    acc[1][0] = __builtin_amdgcn_mfma_f32_32x32x16_bf16(a1, b0, acc[1][0], 0, 0, 0);
    acc[0][1] = __builtin_amdgcn_mfma_f32_32x32x16_bf16(a0, b1, acc[0][1], 0, 0, 0);
    acc[1][1] = __builtin_amdgcn_mfma_f32_32x32x16_bf16(a1, b1, acc[1][1], 0, 0, 0);
    acc[0][2] = __builtin_amdgcn_mfma_f32_32x32x16_bf16(a0, b2, acc[0][2], 0, 0, 0);
    acc[1][2] = __builtin_amdgcn_mfma_f32_32x32x16_bf16(a1, b2, acc[1][2], 0, 0, 0);
    acc[0][3] = __builtin_amdgcn_mfma_f32_32x32x16_bf16(a0, b3, acc[0][3], 0, 0, 0);
    acc[1][3] = __builtin_amdgcn_mfma_f32_32x32x16_bf16(a1, b3, acc[1][3], 0, 0, 0);
  }
}

// ---------------- encoder -----------------------------------------------------
__global__ __launch_bounds__(512, 2) void lstm_encoder(
    const float* __restrict__ speed, const float* __restrict__ pos,
    const float* __restrict__ Wi_s, const float* __restrict__ b_s,
    const float* __restrict__ Wi_p, const float* __restrict__ b_p,
    const short* __restrict__ wpack,
    float* __restrict__ hsum, float* __restrict__ csum,
    short* __restrict__ xchg, int* __restrict__ flags)
{
  __shared__ short hl[64 * 512];   // 65536 B exactly
  int tid = threadIdx.x;
  int b = blockIdx.x;
  int xcd = b & 7, s = b >> 3;
  int P = s & 1, slot = s >> 1;
  int enc = xcd >> 2;
  int gl = (xcd & 3) + (slot << 2);        // 0..63 within this encoder
  int g = enc * 64 + gl;                   // global group 0..127
  int r0 = gl * 64;
  const float* xin = enc ? pos : speed;
  const float* Wi  = enc ? Wi_p : Wi_s;
  const float* bb  = enc ? b_p  : b_s;
  const short* wm = wpack + (size_t)enc * WMAT;
  short* xg = xchg + (size_t)g * XSTR;
  int* myflag = flags + g * 2 + P;
  int* pflag  = flags + g * 2 + (P ^ 1);

  // zero A-tile (h0 = 0)
  #pragma unroll
  for (int i = 0; i < 8; ++i) *(short8*)(hl + (tid + i * 512) * 8) = (short8)0;

  int lane = tid & 63, wv = tid >> 6;
  int arow = lane & 31, ahalf = lane >> 5;
  int sw = arow & 7;
  int ntL = P * 8 + wv;
  const short* bp0 = wm + ntL * 65536 + (lane << 3);
  int colChunkSw = (ntL * 4 + (arow >> 3));           // col>>3, pre-XOR
  int colLow = arow & 7;
  int col = ntL * 32 + arow;

  // x-weights + bias for this lane's 4 gate-rows (n = g*512 + ntL*32 + arow)
  float4 wi4[4]; float bg[4];
  #pragma unroll
  for (int gg = 0; gg < 4; ++gg) {
    int n = gg * 512 + ntL * 32 + arow;
    wi4[gg] = *(const float4*)(Wi + n * 4);
    bg[gg] = bb[n];
  }

  float c_reg[2][16];
  #pragma unroll
  for (int mt = 0; mt < 2; ++mt)
    #pragma unroll
    for (int r = 0; r < 16; ++r) c_reg[mt][r] = 0.0f;

  __syncthreads();

  floatx16 acc[2][4];
  for (int t = 0; t < 16; ++t) {
    gate_mfma(hl, bp0, arow, ahalf, sw, acc);

    float hnew[2][16], cnew[2][16];
    #pragma unroll
    for (int mt = 0; mt < 2; ++mt) {
      #pragma unroll
      for (int r = 0; r < 16; ++r) {
        int row = ((r & 3) + ((r >> 2) << 3) + (ahalf << 2)) + (mt << 5);
        float4 xv = *(const float4*)(xin + (size_t)(r0 + row) * 64 + t * 4);
        float gi = acc[mt][0][r] + wi4[0].x*xv.x + wi4[0].y*xv.y + wi4[0].z*xv.z + wi4[0].w*xv.w + bg[0];
        float gf = acc[mt][1][r] + wi4[1].x*xv.x + wi4[1].y*xv.y + wi4[1].z*xv.z + wi4[1].w*xv.w + bg[1];
        float gg = acc[mt][2][r] + wi4[2].x*xv.x + wi4[2].y*xv.y + wi4[2].z*xv.z + wi4[2].w*xv.w + bg[2];
        float go = acc[mt][3][r] + wi4[3].x*xv.x + wi4[3].y*xv.y + wi4[3].z*xv.z + wi4[3].w*xv.w + bg[3];
        float cn = sigm(gf) * c_reg[mt][r] + sigm(gi) * tanh_f(gg);
        c_reg[mt][r] = cn;
        cnew[mt][r] = cn;
        hnew[mt][r] = sigm(go) * tanh_f(cn);
      }
    }
    __syncthreads();                               // S1: A-tile fully consumed

    if (t < 15) {
      #pragma unroll
      for (int mt = 0; mt < 2; ++mt)
        #pragma unroll
        for (int r = 0; r < 16; ++r) {
          int row = ((r & 3) + ((r >> 2) << 3) + (ahalf << 2)) + (mt << 5);
          unsigned short hb = f2bf(hnew[mt][r]);
          hl[row * 512 + ((colChunkSw ^ (row & 7)) << 3) + colLow] = (short)hb;
          xg[row * 512 + col] = (short)hb;
        }
      __threadfence();
      __syncthreads();                             // S2: all stores drained
      if (tid == 0)
        __hip_atomic_store(myflag, t + 1, __ATOMIC_RELEASE, __HIP_MEMORY_SCOPE_AGENT);
      while (__hip_atomic_load(pflag, __ATOMIC_ACQUIRE, __HIP_MEMORY_SCOPE_AGENT) <= t)
        __builtin_amdgcn_s_sleep(1);
      int Q = P ^ 1;
      #pragma unroll
      for (int p = 0; p < 4; ++p) {
        int row = (tid >> 5) + p * 16;
        int c = tid & 31;
        short8 v = *(const short8*)(xg + row * 512 + Q * 256 + c * 8);
        *(short8*)(hl + row * 512 + (((Q * 32 + c) ^ (row & 7)) << 3)) = v;
      }
      __syncthreads();                             // S3: staging complete
    } else {
      // final: publish fp32 h and c sums for the decoder
      #pragma unroll
      for (int mt = 0; mt < 2; ++mt)
        #pragma unroll
        for (int r = 0; r < 16; ++r) {
          int row = ((r & 3) + ((r >> 2) << 3) + (ahalf << 2)) + (mt << 5);
          atomicAdd(&hsum[(size_t)(r0 + row) * 512 + col], hnew[mt][r]);
          atomicAdd(&csum[(size_t)(r0 + row) * 512 + col], cnew[mt][r]);
        }
    }
  }
}

// ---------------- decoder -----------------------------------------------------
__global__ __launch_bounds__(512, 2) void lstm_decoder(
    const float* __restrict__ speed, const float* __restrict__ pos,
    const float* __restrict__ Wi_ds, const float* __restrict__ b_ds,
    const float* __restrict__ Wi_di, const float* __restrict__ b_di,
    const short* __restrict__ wpack,
    const float* __restrict__ hsum, const float* __restrict__ csum,
    const float* __restrict__ W_fs, const float* __restrict__ b_fs,
    const float* __restrict__ W_fc, const float* __restrict__ b_fc,
    const float* __restrict__ W_emb, const float* __restrict__ b_emb,
    short* __restrict__ xchg, float* __restrict__ xfb, int* __restrict__ flags,
    float* __restrict__ out)
{
  __shared__ short hl[64 * 512];
  int tid = threadIdx.x;
  int b = blockIdx.x;
  int xcd = b & 7, s = b >> 3;
  int P = s & 1, slot = s >> 1;
  int chain = xcd >> 2;
  int gl = (xcd & 3) + (slot << 2);
  int g = chain * 64 + gl;
  int r0 = gl * 64;
  const float* Wi = chain ? Wi_di : Wi_ds;
  const float* bb = chain ? b_di  : b_ds;
  const short* wm = wpack + (size_t)(2 + chain) * WMAT;
  short* xg = xchg + (size_t)g * XSTR;
  float* xf = xfb + (size_t)(g * 2 + P) * 256;
  int* myflag = flags + 512 + g * 2 + P;
  int* pflag  = flags + 512 + g * 2 + (P ^ 1);

  // stage h0 = h_se + h_pe (fp32 sums) into A-tile as bf16
  #pragma unroll
  for (int p = 0; p < 8; ++p) {
    int row = (tid >> 6) + p * 8;
    int ci = tid & 63;
    const float* src = hsum + (size_t)(r0 + row) * 512 + ci * 8;
    float4 f0 = *(const float4*)(src);
    float4 f1 = *(const float4*)(src + 4);
    short8 v;
    v[0] = (short)f2bf(f0.x); v[1] = (short)f2bf(f0.y);
    v[2] = (short)f2bf(f0.z); v[3] = (short)f2bf(f0.w);
    v[4] = (short)f2bf(f1.x); v[5] = (short)f2bf(f1.y);
    v[6] = (short)f2bf(f1.z); v[7] = (short)f2bf(f1.w);
    *(short8*)(hl + row * 512 + ((ci ^ (row & 7)) << 3)) = v;
  }

  int lane = tid & 63, wv = tid >> 6;
  int arow = lane & 31, ahalf = lane >> 5;
  int sw = arow & 7;
  int ntL = P * 8 + wv;
  const short* bp0 = wm + ntL * 65536 + (lane << 3);
  int colChunkSw = (ntL * 4 + (arow >> 3));
  int colLow = arow & 7;
  int col = ntL * 32 + arow;

  float4 wi4[4]; float bg[4];
  #pragma unroll
  for (int gg = 0; gg < 4; ++gg) {
    int n = gg * 512 + ntL * 32 + arow;
    wi4[gg] = *(const float4*)(Wi + n * 4);
    bg[gg] = bb[n];
  }

  float c_reg[2][16];
  #pragma unroll
  for (int mt = 0; mt < 2; ++mt)
    #pragma unroll
    for (int r = 0; r < 16; ++r) {
      int row = ((r & 3) + ((r >> 2) << 3) + (ahalf << 2)) + (mt << 5);
      c_reg[mt][r] = csum[(size_t)(r0 + row) * 512 + col];
    }

  // x(0) = last obs (speed[:,15,:] for chain0, pos[:,15,:] for chain1)
  {
    const float* last = chain ? pos : speed;
    if (tid < 256) {
      int row = tid >> 2, c = tid & 3;
      xf[row * 4 + c] = last[(size_t)(r0 + row) * 64 + 60 + c];
    }
  }
  __syncthreads();

  floatx16 acc[2][4];
  for (int t = 0; t < 32; ++t) {
    gate_mfma(hl, bp0, arow, ahalf, sw, acc);

    float hnew[2][16];
    #pragma unroll
    for (int mt = 0; mt < 2; ++mt) {
      #pragma unroll
      for (int r = 0; r < 16; ++r) {
        int row = ((r & 3) + ((r >> 2) << 3) + (ahalf << 2)) + (mt << 5);
        float4 xv = *(const float4*)(xf + row * 4);
        float gi = acc[mt][0][r] + wi4[0].x*xv.x + wi4[0].y*xv.y + wi4[0].z*xv.z + wi4[0].w*xv.w + bg[0];
        float gf = acc[mt][1][r] + wi4[1].x*xv.x + wi4[1].y*xv.y + wi4[1].z*xv.z + wi4[1].w*xv.w + bg[1];
        float gg = acc[mt][2][r] + wi4[2].x*xv.x + wi4[2].y*xv.y + wi4[2].z*xv.z + wi4[2].w*xv.w + bg[2];
        float go = acc[mt][3][r] + wi4[3].x*xv.x + wi4[3].y*xv.y + wi4[3].z*xv.z + wi4[3].w*xv.w + bg[3];
        float cn = sigm(gf) * c_reg[mt][r] + sigm(gi) * tanh_f(gg);
        c_reg[mt][r] = cn;
        hnew[mt][r] = sigm(go) * tanh_f(cn);
      }
    }
    __syncthreads();                               // S1

    #pragma unroll
    for (int mt = 0; mt < 2; ++mt)
      #pragma unroll
      for (int r = 0; r < 16; ++r) {
        int row = ((r & 3) + ((r >> 2) << 3) + (ahalf << 2)) + (mt << 5);
        unsigned short hb = f2bf(hnew[mt][r]);
        hl[row * 512 + ((colChunkSw ^ (row & 7)) << 3) + colLow] = (short)hb;
        xg[row * 512 + col] = (short)hb;
      }
    __threadfence();
    __syncthreads();                               // S2
    if (tid == 0)
      __hip_atomic_store(myflag, t + 1, __ATOMIC_RELEASE, __HIP_MEMORY_SCOPE_AGENT);
    while (__hip_atomic_load(pflag, __ATOMIC_ACQUIRE, __HIP_MEMORY_SCOPE_AGENT) <= t)
      __builtin_amdgcn_s_sleep(1);
    {
      int Q = P ^ 1;
      #pragma unroll
      for (int p = 0; p < 4; ++p) {
        int row = (tid >> 5) + p * 16;
        int c = tid & 31;
        short8 v = *(const short8*)(xg + row * 512 + Q * 256 + c * 8);
        *(short8*)(hl + row * 512 + (((Q * 32 + c) ^ (row & 7)) << 3)) = v;
      }
    }
    __syncthreads();                               // S3: full h(t+1) in LDS

    // heads on h(t+1): outputs index t; feedback x(t+1). Both P compute
    // (dup avoids a second sync round); only P0 writes outputs.
    if (chain == 0) {
      float w0[8], w1[8], w2[8], w3[8];
      #pragma unroll
      for (int j = 0; j < 4; ++j) {
        float4 a0 = *(const float4*)(W_fs + 0 * 512 + lane * 8 + j * 0); (void)a0; break;
      }
      // reload per step (keeps MFMA-phase register pressure down)
      {
        float4 a, c2;
        a = *(const float4*)(W_fs + 0 * 512 + lane * 8); c2 = *(const float4*)(W_fs + 0 * 512 + lane * 8 + 4);
        w0[0]=a.x; w0[1]=a.y; w0[2]=a.z; w0[3]=a.w; w0[4]=c2.x; w0[5]=c2.y; w0[6]=c2.z; w0[7]=c2.w;
        a = *(const float4*)(W_fs + 1 * 512 + lane * 8); c2 = *(const float4*)(W_fs + 1 * 512 + lane * 8 + 4);
        w1[0]=a.x; w1[1]=a.y; w1[2]=a.z; w1[3]=a.w; w1[4]=c2.x; w1[5]=c2.y; w1[6]=c2.z; w1[7]=c2.w;
        a = *(const float4*)(W_fs + 2 * 512 + lane * 8); c2 = *(const float4*)(W_fs + 2 * 512 + lane * 8 + 4);
        w2[0]=a.x; w2[1]=a.y; w2[2]=a.z; w2[3]=a.w; w2[4]=c2.x; w2[5]=c2.y; w2[6]=c2.z; w2[7]=c2.w;
        a = *(const float4*)(W_fs + 3 * 512 + lane * 8); c2 = *(const float4*)(W_fs + 3 * 512 + lane * 8 + 4);
        w3[0]=a.x; w3[1]=a.y; w3[2]=a.z; w3[3]=a.w; w3[4]=c2.x; w3[5]=c2.y; w3[6]=c2.z; w3[7]=c2.w;
      }
      float hb0 = b_fs[0], hb1 = b_fs[1], hb2 = b_fs[2], hb3 = b_fs[3];
      #pragma unroll 1
      for (int i = 0; i < 8; ++i) {
        int row = wv * 8 + i;
        short8 hv8 = *(const short8*)(hl + row * 512 + ((lane ^ (row & 7)) << 3));
        float p0 = 0.f, p1 = 0.f, p2 = 0.f, p3 = 0.f;
        #pragma unroll
        for (int j = 0; j < 8; ++j) {
          float hv = bf2f((unsigned short)hv8[j]);
          p0 += hv * w0[j]; p1 += hv * w1[j]; p2 += hv * w2[j]; p3 += hv * w3[j];
        }
        #pragma unroll
        for (int off = 32; off > 0; off >>= 1) {
          p0 += __shfl_xor(p0, off); p1 += __shfl_xor(p1, off);
          p2 += __shfl_xor(p2, off); p3 += __shfl_xor(p3, off);
        }
        float s0 = fminf(fmaxf(p0 + hb0, -100.0f), 100.0f);
        float s1 = fminf(fmaxf(p1 + hb1, -100.0f), 100.0f);
        float s2 = fminf(fmaxf(p2 + hb2, -100.0f), 100.0f);
        float s3 = fminf(fmaxf(p3 + hb3, -100.0f), 100.0f);
        if (lane < 4) {
          float v = (lane == 0) ? s0 : (lane == 1) ? s1 : (lane == 2) ? s2 : s3;
          xf[row * 4 + lane] = v;
          if (P == 0) out[(size_t)(r0 + row) * 128 + t * 4 + lane] = v;
        }
      }
    } else {
      float w0[8], w1[8];
      {
        float4 a, c2;
        a = *(const float4*)(W_fc + 0 * 512 + lane * 8); c2 = *(const float4*)(W_fc + 0 * 512 + lane * 8 + 4);
        w0[0]=a.x; w0[1]=a.y; w0[2]=a.z; w0[3]=a.w; w0[4]=c2.x; w0[5]=c2.y; w0[6]=c2.z; w0[7]=c2.w;
        a = *(const float4*)(W_fc + 1 * 512 + lane * 8); c2 = *(const float4*)(W_fc + 1 * 512 + lane * 8 + 4);
        w1[0]=a.x; w1[1]=a.y; w1[2]=a.z; w1[3]=a.w; w1[4]=c2.x; w1[5]=c2.y; w1[6]=c2.z; w1[7]=c2.w;
      }
      float hb0 = b_fc[0], hb1 = b_fc[1];
      float we0 = W_emb[0], we1 = W_emb[1], we2 = W_emb[2], we3 = W_emb[3];
      float we4 = W_emb[4], we5 = W_emb[5], we6 = W_emb[6], we7 = W_emb[7];
      float be0 = b_emb[0], be1 = b_emb[1], be2 = b_emb[2], be3 = b_emb[3];
      #pragma unroll 1
      for (int i = 0; i < 8; ++i) {
        int row = wv * 8 + i;
        short8 hv8 = *(const short8*)(hl + row * 512 + ((lane ^ (row & 7)) << 3));
        float p0 = 0.f, p1 = 0.f;
        #pragma unroll
        for (int j = 0; j < 8; ++j) {
          float hv = bf2f((unsigned short)hv8[j]);
          p0 += hv * w0[j]; p1 += hv * w1[j];
        }
        #pragma unroll
        for (int off = 32; off > 0; off >>= 1) {
          p0 += __shfl_xor(p0, off); p1 += __shfl_xor(p1, off);
        }
        float it0 = fmaxf(p0 + hb0, 0.0f);
        float it1 = fmaxf(p1 + hb1, 0.0f);
        if (lane < 4) {
          float wa = (lane == 0) ? we0 : (lane == 1) ? we2 : (lane == 2) ? we4 : we6;
          float wb = (lane == 0) ? we1 : (lane == 1) ? we3 : (lane == 2) ? we5 : we7;
          float bo = (lane == 0) ? be0 : (lane == 1) ? be1 : (lane == 2) ? be2 : be3;
          xf[row * 4 + lane] = fmaxf(wa * it0 + wb * it1 + bo, 0.0f);
        }
        if (t == 31 && P == 0 && lane < 2) {
          float m = fmaxf(it0, it1);
          float e0 = __expf(it0 - m), e1 = __expf(it1 - m);
          float v = ((lane == 0) ? e0 : e1) * rcpf(e0 + e1);
          out[(size_t)524288 + (size_t)(r0 + row) * 2 + lane] = v;
        }
      }
    }
    __syncthreads();                               // S4: xf/hl safe for next iter
  }
}

extern "C" void kernel_launch(void* const* d_in, const int* in_sizes, int n_in,
                              void* d_out, int out_size, void* d_ws, size_t ws_size,
                              hipStream_t stream)
{
  const float* speed    = (const float*)d_in[0];
  const float* pos      = (const float*)d_in[1];
  const float* enc_s_Wi = (const float*)d_in[2];
  const float* enc_s_Wh = (const float*)d_in[3];
  const float* enc_s_b  = (const float*)d_in[4];
  const float* enc_p_Wi = (const float*)d_in[5];
  const float* enc_p_Wh = (const float*)d_in[6];
  const float* enc_p_b  = (const float*)d_in[7];
  const float* dec_s_Wi = (const float*)d_in[8];
  const float* dec_s_Wh = (const float*)d_in[9];
  const float* dec_s_b  = (const float*)d_in[10];
  const float* dec_i_Wi = (const float*)d_in[11];
  const float* dec_i_Wh = (const float*)d_in[12];
  const float* dec_i_b  = (const float*)d_in[13];
  const float* W_fs     = (const float*)d_in[14];
  const float* b_fs     = (const float*)d_in[15];
  const float* W_fc     = (const float*)d_in[16];
  const float* b_fc     = (const float*)d_in[17];
  const float* W_emb    = (const float*)d_in[18];
  const float* b_emb    = (const float*)d_in[19];
  float* out = (float*)d_out;

  char* ws = (char*)d_ws;
  short* wpack = (short*)ws;                       //  8,388,608 B
  float* hsum  = (float*)(ws + 8388608);           //  8,388,608 B
  float* csum  = (float*)(ws + 16777216);          //  8,388,608 B
  short* xchg  = (short*)(ws + 25165824);          //  8,388,608 B
  float* xfb   = (float*)(ws + 33554432);          //    262,144 B
  int*   flags = (int*)(ws + 33816576);            //      4,096 B

  prep_weights<<<16384, 256, 0, stream>>>(
      enc_s_Wh, enc_p_Wh, dec_s_Wh, dec_i_Wh, wpack, hsum, csum, flags);
  lstm_encoder<<<256, 512, 0, stream>>>(
      speed, pos, enc_s_Wi, enc_s_b, enc_p_Wi, enc_p_b, wpack, hsum, csum,
      xchg, flags);
  lstm_decoder<<<256, 512, 0, stream>>>(
      speed, pos, dec_s_Wi, dec_s_b, dec_i_Wi, dec_i_b, wpack, hsum, csum,
      W_fs, b_fs, W_fc, b_fc, W_emb, b_emb, xchg, xfb, flags, out);
}

// Round 4
// 3393.864 us; speedup vs baseline: 1.8214x; 1.8214x over previous
//
#include <hip/hip_runtime.h>
#include <stdint.h>

// R4: sync-free 64-rows/block, full-N per block, 128 blocks.
// - Halves per-XCD L2 weight traffic vs 32-row blocks (16 blocks/XCD x 2.1 MB).
// - Double-buffered A-tile in dynamic LDS (2 x 64 x 520 shorts = 133120 B):
//   no write-after-read barrier; encoder 1 barrier/step, decoder 2.
// - K=512 exact; x@Wi.T + b applied in fp32 epilogue (better precision too).
// - NO cross-workgroup sync (R3's agent-scope acquire nuked L2 every step:
//   FETCH_SIZE 34->848 MB. Never again.)

#define LROW 520              // padded row stride (shorts); R2-proven ~0 conflicts
#define BUF_SH (64 * LROW)    // 33280 shorts per buffer
#define WMAT 1048576          // shorts per packed matrix (16 ntL * 32 kt * 4 g * 512)
#define B_TOT 4096

typedef __attribute__((ext_vector_type(8))) short short8;
typedef __attribute__((ext_vector_type(16))) float floatx16;

__device__ __forceinline__ unsigned short f2bf(float x) {
  union { float f; unsigned int u; } v; v.f = x;
  unsigned int u = v.u;
  return (unsigned short)((u + 0x7FFFu + ((u >> 16) & 1u)) >> 16);
}
__device__ __forceinline__ float bf2f(unsigned short s) {
  union { unsigned int u; float f; } v; v.u = ((unsigned int)s) << 16;
  return v.f;
}
__device__ __forceinline__ float rcpf(float x) { return __builtin_amdgcn_rcpf(x); }
__device__ __forceinline__ float sigm(float x) { return rcpf(1.0f + __expf(-x)); }
__device__ __forceinline__ float tanh_f(float x) {
  return 1.0f - 2.0f * rcpf(1.0f + __expf(2.0f * x));
}

// ---------------- prep: pack Wh (bf16, MFMA-B layout) ------------------------
// idx = ((ntL*32 + kt)*4 + g)*512 + lanep*8 + ks
//   n = g*512 + ntL*32 + ni; kt = ka>>4; kh = (ka>>3)&1; ks = ka&7; lanep = kh*32+ni
__global__ void prep_weights(
    const float* __restrict__ Wh_s, const float* __restrict__ Wh_p,
    const float* __restrict__ Wh_d, const float* __restrict__ Wh_i,
    short* __restrict__ wpack)
{
  int idx = blockIdx.x * 256 + threadIdx.x;
  const int per = 2048 * 512;
  if (idx >= 4 * per) return;
  int mat = idx / per;
  int rem = idx - mat * per;
  int n = rem >> 9;
  int ka = rem & 511;
  const float* Wh = (mat == 0) ? Wh_s : (mat == 1) ? Wh_p : (mat == 2) ? Wh_d : Wh_i;
  float v = Wh[n * 512 + ka];
  int g = n >> 9, ntL = (n >> 5) & 15, ni = n & 31;
  int kt = ka >> 4, kh = (ka >> 3) & 1, ks = ka & 7;
  int lanep = kh * 32 + ni;
  wpack[(size_t)mat * WMAT + ((((ntL * 32 + kt) * 4 + g) << 9) + (lanep << 3) + ks)] =
      (short)f2bf(v);
}

// ---------------- gate matmul: one ntL slice, 2 M-tiles, 4 gates, K=512 ------
__device__ __forceinline__ void gate_mfma(
    const short* cur, const short* __restrict__ bp0,
    int arow, int ahalf, floatx16 acc[2][4])
{
  #pragma unroll
  for (int mt = 0; mt < 2; ++mt)
    #pragma unroll
    for (int g = 0; g < 4; ++g) acc[mt][g] = (floatx16)0.0f;
  const short* bp = bp0;
  const short* ap = cur + arow * LROW + ahalf * 8;
  #pragma unroll 4
  for (int kt = 0; kt < 32; ++kt) {
    short8 a0 = *(const short8*)(ap + kt * 16);
    short8 a1 = *(const short8*)(ap + 32 * LROW + kt * 16);
    short8 b0 = *(const short8*)(bp);
    short8 b1 = *(const short8*)(bp + 512);
    short8 b2 = *(const short8*)(bp + 1024);
    short8 b3 = *(const short8*)(bp + 1536);
    bp += 2048;
    acc[0][0] = __builtin_amdgcn_mfma_f32_32x32x16_bf16(a0, b0, acc[0][0], 0, 0, 0);
    acc[1][0] = __builtin_amdgcn_mfma_f32_32x32x16_bf16(a1, b0, acc[1][0], 0, 0, 0);
    acc[0][1] = __builtin_amdgcn_mfma_f32_32x32x16_bf16(a0, b1, acc[0][1], 0, 0, 0);
    acc[1][1] = __builtin_amdgcn_mfma_f32_32x32x16_bf16(a1, b1, acc[1][1], 0, 0, 0);
    acc[0][2] = __builtin_amdgcn_mfma_f32_32x32x16_bf16(a0, b2, acc[0][2], 0, 0, 0);
    acc[1][2] = __builtin_amdgcn_mfma_f32_32x32x16_bf16(a1, b2, acc[1][2], 0, 0, 0);
    acc[0][3] = __builtin_amdgcn_mfma_f32_32x32x16_bf16(a0, b3, acc[0][3], 0, 0, 0);
    acc[1][3] = __builtin_amdgcn_mfma_f32_32x32x16_bf16(a1, b3, acc[1][3], 0, 0, 0);
  }
}

// ---------------- encoder: 128 blocks, 64 rows each ---------------------------
__global__ __launch_bounds__(512, 2) void lstm_encoder(
    const float* __restrict__ speed, const float* __restrict__ pos,
    const float* __restrict__ Wi_s, const float* __restrict__ b_s,
    const float* __restrict__ Wi_p, const float* __restrict__ b_p,
    const short* __restrict__ wpack,
    short* __restrict__ h_enc, float* __restrict__ c_enc)
{
  extern __shared__ short smem[];
  short* bufA = smem;
  short* bufB = smem + BUF_SH;
  int tid = threadIdx.x;
  int b = blockIdx.x;
  int enc = (b & 7) >> 2;                    // XCDs 0-3: speed, 4-7: pos
  int gl = (b & 3) + ((b >> 3) << 2);        // 0..63
  int r0 = gl * 64;
  const float* xin = enc ? pos : speed;
  const float* Wi  = enc ? Wi_p : Wi_s;
  const float* bb  = enc ? b_p  : b_s;
  const short* wm = wpack + (size_t)enc * WMAT;

  for (int i = tid; i < BUF_SH; i += 512) bufA[i] = 0;   // h0 = 0

  int lane = tid & 63, wv = tid >> 6;
  int arow = lane & 31, ahalf = lane >> 5;

  float c_reg[2][2][16];
  #pragma unroll
  for (int jt = 0; jt < 2; ++jt)
    #pragma unroll
    for (int mt = 0; mt < 2; ++mt)
      #pragma unroll
      for (int r = 0; r < 16; ++r) c_reg[jt][mt][r] = 0.0f;

  __syncthreads();

  for (int t = 0; t < 16; ++t) {
    const short* cur = (t & 1) ? bufB : bufA;
    short* nxt = (t & 1) ? bufA : bufB;
    #pragma unroll 1
    for (int jt = 0; jt < 2; ++jt) {
      int ntL = wv * 2 + jt;
      floatx16 acc[2][4];
      gate_mfma(cur, wm + ntL * 65536 + (lane << 3), arow, ahalf, acc);
      float4 wi4[4]; float bg[4];
      #pragma unroll
      for (int gg = 0; gg < 4; ++gg) {
        int n = gg * 512 + ntL * 32 + arow;
        wi4[gg] = *(const float4*)(Wi + n * 4);
        bg[gg] = bb[n];
      }
      int colw = ntL * 32 + arow;
      #pragma unroll
      for (int mt = 0; mt < 2; ++mt) {
        #pragma unroll
        for (int r = 0; r < 16; ++r) {
          int row = (r & 3) + ((r >> 2) << 3) + (ahalf << 2) + (mt << 5);
          float4 xv = *(const float4*)(xin + (size_t)(r0 + row) * 64 + t * 4);
          float gi = acc[mt][0][r] + wi4[0].x*xv.x + wi4[0].y*xv.y + wi4[0].z*xv.z + wi4[0].w*xv.w + bg[0];
          float gf = acc[mt][1][r] + wi4[1].x*xv.x + wi4[1].y*xv.y + wi4[1].z*xv.z + wi4[1].w*xv.w + bg[1];
          float gg2= acc[mt][2][r] + wi4[2].x*xv.x + wi4[2].y*xv.y + wi4[2].z*xv.z + wi4[2].w*xv.w + bg[2];
          float go = acc[mt][3][r] + wi4[3].x*xv.x + wi4[3].y*xv.y + wi4[3].z*xv.z + wi4[3].w*xv.w + bg[3];
          float cn = sigm(gf) * c_reg[jt][mt][r] + sigm(gi) * tanh_f(gg2);
          c_reg[jt][mt][r] = cn;
          nxt[row * LROW + colw] = (short)f2bf(sigm(go) * tanh_f(cn));
        }
      }
    }
    __syncthreads();
  }

  // h(16) is in bufA (t=15 wrote nxt=bufA). Store h (bf16) + c (fp32).
  for (int i = tid; i < 4096; i += 512) {
    int row = i >> 6, ch = i & 63;
    *(short8*)(h_enc + ((size_t)(enc * B_TOT + r0 + row) << 9) + ch * 8) =
        *(const short8*)(bufA + row * LROW + ch * 8);
  }
  #pragma unroll
  for (int jt = 0; jt < 2; ++jt) {
    int colw = (wv * 2 + jt) * 32 + arow;
    #pragma unroll
    for (int mt = 0; mt < 2; ++mt)
      #pragma unroll
      for (int r = 0; r < 16; ++r) {
        int row = (r & 3) + ((r >> 2) << 3) + (ahalf << 2) + (mt << 5);
        c_enc[((size_t)(enc * B_TOT + r0 + row) << 9) + colw] = c_reg[jt][mt][r];
      }
  }
}

// ---------------- decoder: 128 blocks, 64 rows each ---------------------------
__global__ __launch_bounds__(512, 2) void lstm_decoder(
    const float* __restrict__ speed, const float* __restrict__ pos,
    const float* __restrict__ Wi_ds, const float* __restrict__ b_ds,
    const float* __restrict__ Wi_di, const float* __restrict__ b_di,
    const short* __restrict__ wpack,
    const short* __restrict__ h_enc, const float* __restrict__ c_enc,
    const float* __restrict__ W_fs, const float* __restrict__ b_fs,
    const float* __restrict__ W_fc, const float* __restrict__ b_fc,
    const float* __restrict__ W_emb, const float* __restrict__ b_emb,
    float* __restrict__ out)
{
  extern __shared__ short smem[];
  short* bufA = smem;
  short* bufB = smem + BUF_SH;
  float* xf = (float*)(smem + 2 * BUF_SH);   // 64 rows x 4 floats
  int tid = threadIdx.x;
  int b = blockIdx.x;
  int chain = (b & 7) >> 2;                  // XCDs 0-3: speed chain, 4-7: crossing
  int gl = (b & 3) + ((b >> 3) << 2);
  int r0 = gl * 64;
  const float* Wi = chain ? Wi_di : Wi_ds;
  const float* bb = chain ? b_di  : b_ds;
  const short* wm = wpack + (size_t)(2 + chain) * WMAT;

  // stage h0 = h_se + h_pe into bufA (bf16)
  for (int i = tid; i < 4096; i += 512) {
    int row = i >> 6, ch = i & 63;
    const short* s0 = h_enc + ((size_t)(r0 + row) << 9) + ch * 8;
    const short* s1 = h_enc + ((size_t)(B_TOT + r0 + row) << 9) + ch * 8;
    short8 a = *(const short8*)s0;
    short8 c2 = *(const short8*)s1;
    short8 v;
    #pragma unroll
    for (int j = 0; j < 8; ++j)
      v[j] = (short)f2bf(bf2f((unsigned short)a[j]) + bf2f((unsigned short)c2[j]));
    *(short8*)(bufA + row * LROW + ch * 8) = v;
  }

  int lane = tid & 63, wv = tid >> 6;
  int arow = lane & 31, ahalf = lane >> 5;

  float c_reg[2][2][16];
  #pragma unroll
  for (int jt = 0; jt < 2; ++jt) {
    int colw = (wv * 2 + jt) * 32 + arow;
    #pragma unroll
    for (int mt = 0; mt < 2; ++mt)
      #pragma unroll
      for (int r = 0; r < 16; ++r) {
        int row = (r & 3) + ((r >> 2) << 3) + (ahalf << 2) + (mt << 5);
        size_t gi = ((size_t)(r0 + row) << 9) + colw;
        c_reg[jt][mt][r] = c_enc[gi] + c_enc[gi + (((size_t)B_TOT) << 9)];
      }
  }

  // x(0) = last observation
  {
    const float* last = chain ? pos : speed;
    if (tid < 256) {
      int row = tid >> 2, c = tid & 3;
      xf[row * 4 + c] = last[(size_t)(r0 + row) * 64 + 60 + c];
    }
  }
  __syncthreads();

  for (int t = 0; t < 32; ++t) {
    const short* cur = (t & 1) ? bufB : bufA;
    short* nxt = (t & 1) ? bufA : bufB;
    #pragma unroll 1
    for (int jt = 0; jt < 2; ++jt) {
      int ntL = wv * 2 + jt;
      floatx16 acc[2][4];
      gate_mfma(cur, wm + ntL * 65536 + (lane << 3), arow, ahalf, acc);
      float4 wi4[4]; float bg[4];
      #pragma unroll
      for (int gg = 0; gg < 4; ++gg) {
        int n = gg * 512 + ntL * 32 + arow;
        wi4[gg] = *(const float4*)(Wi + n * 4);
        bg[gg] = bb[n];
      }
      int colw = ntL * 32 + arow;
      #pragma unroll
      for (int mt = 0; mt < 2; ++mt) {
        #pragma unroll
        for (int r = 0; r < 16; ++r) {
          int row = (r & 3) + ((r >> 2) << 3) + (ahalf << 2) + (mt << 5);
          float4 xv = *(const float4*)(xf + row * 4);
          float gi = acc[mt][0][r] + wi4[0].x*xv.x + wi4[0].y*xv.y + wi4[0].z*xv.z + wi4[0].w*xv.w + bg[0];
          float gf = acc[mt][1][r] + wi4[1].x*xv.x + wi4[1].y*xv.y + wi4[1].z*xv.z + wi4[1].w*xv.w + bg[1];
          float gg2= acc[mt][2][r] + wi4[2].x*xv.x + wi4[2].y*xv.y + wi4[2].z*xv.z + wi4[2].w*xv.w + bg[2];
          float go = acc[mt][3][r] + wi4[3].x*xv.x + wi4[3].y*xv.y + wi4[3].z*xv.z + wi4[3].w*xv.w + bg[3];
          float cn = sigm(gf) * c_reg[jt][mt][r] + sigm(gi) * tanh_f(gg2);
          c_reg[jt][mt][r] = cn;
          nxt[row * LROW + colw] = (short)f2bf(sigm(go) * tanh_f(cn));
        }
      }
    }
    __syncthreads();                         // h(t+1) complete in nxt

    // heads on h(t+1): wave wv handles rows [wv*8, wv*8+8)
    if (chain == 0) {
      float w0[8], w1[8], w2[8], w3[8];
      {
        float4 a, c2;
        a = *(const float4*)(W_fs + 0 * 512 + lane * 8); c2 = *(const float4*)(W_fs + 0 * 512 + lane * 8 + 4);
        w0[0]=a.x; w0[1]=a.y; w0[2]=a.z; w0[3]=a.w; w0[4]=c2.x; w0[5]=c2.y; w0[6]=c2.z; w0[7]=c2.w;
        a = *(const float4*)(W_fs + 1 * 512 + lane * 8); c2 = *(const float4*)(W_fs + 1 * 512 + lane * 8 + 4);
        w1[0]=a.x; w1[1]=a.y; w1[2]=a.z; w1[3]=a.w; w1[4]=c2.x; w1[5]=c2.y; w1[6]=c2.z; w1[7]=c2.w;
        a = *(const float4*)(W_fs + 2 * 512 + lane * 8); c2 = *(const float4*)(W_fs + 2 * 512 + lane * 8 + 4);
        w2[0]=a.x; w2[1]=a.y; w2[2]=a.z; w2[3]=a.w; w2[4]=c2.x; w2[5]=c2.y; w2[6]=c2.z; w2[7]=c2.w;
        a = *(const float4*)(W_fs + 3 * 512 + lane * 8); c2 = *(const float4*)(W_fs + 3 * 512 + lane * 8 + 4);
        w3[0]=a.x; w3[1]=a.y; w3[2]=a.z; w3[3]=a.w; w3[4]=c2.x; w3[5]=c2.y; w3[6]=c2.z; w3[7]=c2.w;
      }
      float hb0 = b_fs[0], hb1 = b_fs[1], hb2 = b_fs[2], hb3 = b_fs[3];
      #pragma unroll 1
      for (int i = 0; i < 8; ++i) {
        int row = wv * 8 + i;
        short8 hv8 = *(const short8*)(nxt + row * LROW + lane * 8);
        float p0 = 0.f, p1 = 0.f, p2 = 0.f, p3 = 0.f;
        #pragma unroll
        for (int j = 0; j < 8; ++j) {
          float hv = bf2f((unsigned short)hv8[j]);
          p0 += hv * w0[j]; p1 += hv * w1[j]; p2 += hv * w2[j]; p3 += hv * w3[j];
        }
        #pragma unroll
        for (int off = 32; off > 0; off >>= 1) {
          p0 += __shfl_xor(p0, off); p1 += __shfl_xor(p1, off);
          p2 += __shfl_xor(p2, off); p3 += __shfl_xor(p3, off);
        }
        float s0 = fminf(fmaxf(p0 + hb0, -100.0f), 100.0f);
        float s1 = fminf(fmaxf(p1 + hb1, -100.0f), 100.0f);
        float s2 = fminf(fmaxf(p2 + hb2, -100.0f), 100.0f);
        float s3 = fminf(fmaxf(p3 + hb3, -100.0f), 100.0f);
        if (lane < 4) {
          float v = (lane == 0) ? s0 : (lane == 1) ? s1 : (lane == 2) ? s2 : s3;
          xf[row * 4 + lane] = v;
          out[(size_t)(r0 + row) * 128 + t * 4 + lane] = v;
        }
      }
    } else {
      float w0[8], w1[8];
      {
        float4 a, c2;
        a = *(const float4*)(W_fc + 0 * 512 + lane * 8); c2 = *(const float4*)(W_fc + 0 * 512 + lane * 8 + 4);
        w0[0]=a.x; w0[1]=a.y; w0[2]=a.z; w0[3]=a.w; w0[4]=c2.x; w0[5]=c2.y; w0[6]=c2.z; w0[7]=c2.w;
        a = *(const float4*)(W_fc + 1 * 512 + lane * 8); c2 = *(const float4*)(W_fc + 1 * 512 + lane * 8 + 4);
        w1[0]=a.x; w1[1]=a.y; w1[2]=a.z; w1[3]=a.w; w1[4]=c2.x; w1[5]=c2.y; w1[6]=c2.z; w1[7]=c2.w;
      }
      float hb0 = b_fc[0], hb1 = b_fc[1];
      float we0 = W_emb[0], we1 = W_emb[1], we2 = W_emb[2], we3 = W_emb[3];
      float we4 = W_emb[4], we5 = W_emb[5], we6 = W_emb[6], we7 = W_emb[7];
      float be0 = b_emb[0], be1 = b_emb[1], be2 = b_emb[2], be3 = b_emb[3];
      #pragma unroll 1
      for (int i = 0; i < 8; ++i) {
        int row = wv * 8 + i;
        short8 hv8 = *(const short8*)(nxt + row * LROW + lane * 8);
        float p0 = 0.f, p1 = 0.f;
        #pragma unroll
        for (int j = 0; j < 8; ++j) {
          float hv = bf2f((unsigned short)hv8[j]);
          p0 += hv * w0[j]; p1 += hv * w1[j];
        }
        #pragma unroll
        for (int off = 32; off > 0; off >>= 1) {
          p0 += __shfl_xor(p0, off); p1 += __shfl_xor(p1, off);
        }
        float it0 = fmaxf(p0 + hb0, 0.0f);
        float it1 = fmaxf(p1 + hb1, 0.0f);
        if (lane < 4) {
          float wa = (lane == 0) ? we0 : (lane == 1) ? we2 : (lane == 2) ? we4 : we6;
          float wb = (lane == 0) ? we1 : (lane == 1) ? we3 : (lane == 2) ? we5 : we7;
          float bo = (lane == 0) ? be0 : (lane == 1) ? be1 : (lane == 2) ? be2 : be3;
          xf[row * 4 + lane] = fmaxf(wa * it0 + wb * it1 + bo, 0.0f);
        }
        if (t == 31 && lane < 2) {
          float m = fmaxf(it0, it1);
          float e0 = __expf(it0 - m), e1 = __expf(it1 - m);
          float v = ((lane == 0) ? e0 : e1) * rcpf(e0 + e1);
          out[(size_t)524288 + (size_t)(r0 + row) * 2 + lane] = v;
        }
      }
    }
    __syncthreads();                         // xf ready; cur free for rewrite
  }
}

extern "C" void kernel_launch(void* const* d_in, const int* in_sizes, int n_in,
                              void* d_out, int out_size, void* d_ws, size_t ws_size,
                              hipStream_t stream)
{
  const float* speed    = (const float*)d_in[0];
  const float* pos      = (const float*)d_in[1];
  const float* enc_s_Wi = (const float*)d_in[2];
  const float* enc_s_Wh = (const float*)d_in[3];
  const float* enc_s_b  = (const float*)d_in[4];
  const float* enc_p_Wi = (const float*)d_in[5];
  const float* enc_p_Wh = (const float*)d_in[6];
  const float* enc_p_b  = (const float*)d_in[7];
  const float* dec_s_Wi = (const float*)d_in[8];
  const float* dec_s_Wh = (const float*)d_in[9];
  const float* dec_s_b  = (const float*)d_in[10];
  const float* dec_i_Wi = (const float*)d_in[11];
  const float* dec_i_Wh = (const float*)d_in[12];
  const float* dec_i_b  = (const float*)d_in[13];
  const float* W_fs     = (const float*)d_in[14];
  const float* b_fs     = (const float*)d_in[15];
  const float* W_fc     = (const float*)d_in[16];
  const float* b_fc     = (const float*)d_in[17];
  const float* W_emb    = (const float*)d_in[18];
  const float* b_emb    = (const float*)d_in[19];
  float* out = (float*)d_out;

  char* ws = (char*)d_ws;
  short* wpack = (short*)ws;                       //  8,388,608 B
  short* h_enc = (short*)(ws + 8388608);           //  8,388,608 B (2 x 4096 x 512 bf16)
  float* c_enc = (float*)(ws + 16777216);          // 16,777,216 B (2 x 4096 x 512 f32)

  const int dynLDS = 2 * BUF_SH * 2 + 1024;        // 134,144 B
  hipFuncSetAttribute((const void*)lstm_encoder,
                      hipFuncAttributeMaxDynamicSharedMemorySize, dynLDS);
  hipFuncSetAttribute((const void*)lstm_decoder,
                      hipFuncAttributeMaxDynamicSharedMemorySize, dynLDS);

  prep_weights<<<16384, 256, 0, stream>>>(
      enc_s_Wh, enc_p_Wh, dec_s_Wh, dec_i_Wh, wpack);
  lstm_encoder<<<128, 512, dynLDS, stream>>>(
      speed, pos, enc_s_Wi, enc_s_b, enc_p_Wi, enc_p_b, wpack, h_enc, c_enc);
  lstm_decoder<<<128, 512, dynLDS, stream>>>(
      speed, pos, dec_s_Wi, dec_s_b, dec_i_Wi, dec_i_b, wpack, h_enc, c_enc,
      W_fs, b_fs, W_fc, b_fc, W_emb, b_emb, out);
}